// Round 1
// 4262.226 us; speedup vs baseline: 1.0547x; 1.0547x over previous
//
#include <hip/hip_runtime.h>
#include <math.h>

// Shapes (fixed per reference setup_inputs):
#define BB 32
#define SFULL 513
#define TT 512
#define DD 1024
#define KK 256
#define VV 256
#define HH 2048
#define OO 256

// ---------------------------------------------------------------------------
// Generic tiled GEMM: C[m][n] = sum_k A[m][k] * B[n][k]   (A * B^T)
// 64x64 tile, BK=16, 256 threads, 4x4 micro-tile per thread.
// Batch via blockIdx.z with element strides. Accumulation in CT.
// All dims assumed divisible (M%64==0, N%64==0, K%16==0) — true for all uses.
// ---------------------------------------------------------------------------
template <typename AT, typename BT, typename CT>
__global__ __launch_bounds__(256) void gemm_abt(
    const AT* __restrict__ A, long long aBatch, int aPitch,
    const BT* __restrict__ Bm, long long bBatch, int bPitch,
    CT* __restrict__ C, long long cBatch, int cPitch, int Kd) {
  const int bz = blockIdx.z;
  A  += (size_t)bz * aBatch;
  Bm += (size_t)bz * bBatch;
  C  += (size_t)bz * cBatch;
  const int m0 = blockIdx.y * 64;
  const int n0 = blockIdx.x * 64;
  const int tid = threadIdx.x;
  const int tx = tid & 15;        // 0..15 -> n
  const int ty = tid >> 4;        // 0..15 -> m
  const int rl = tid >> 2;        // 0..63 row for loads
  const int kq = tid & 3;         // 0..3  k-quad for loads

  __shared__ AT As[16][65];
  __shared__ BT Bs[16][65];

  CT acc[4][4];
#pragma unroll
  for (int i = 0; i < 4; i++)
#pragma unroll
    for (int j = 0; j < 4; j++) acc[i][j] = (CT)0;

  for (int kk = 0; kk < Kd; kk += 16) {
    const AT* ap = A + (size_t)(m0 + rl) * aPitch + kk + kq * 4;
    const BT* bp = Bm + (size_t)(n0 + rl) * bPitch + kk + kq * 4;
#pragma unroll
    for (int i = 0; i < 4; i++) As[kq * 4 + i][rl] = ap[i];
#pragma unroll
    for (int i = 0; i < 4; i++) Bs[kq * 4 + i][rl] = bp[i];
    __syncthreads();
#pragma unroll
    for (int k = 0; k < 16; k++) {
      CT a[4], b[4];
#pragma unroll
      for (int i = 0; i < 4; i++) a[i] = (CT)As[k][ty * 4 + i];
#pragma unroll
      for (int j = 0; j < 4; j++) b[j] = (CT)Bs[k][tx * 4 + j];
#pragma unroll
      for (int i = 0; i < 4; i++)
#pragma unroll
        for (int j = 0; j < 4; j++) acc[i][j] += a[i] * b[j];
    }
    __syncthreads();
  }

#pragma unroll
  for (int i = 0; i < 4; i++) {
    CT* cp = C + (size_t)(m0 + ty * 4 + i) * cPitch + n0 + tx * 4;
#pragma unroll
    for (int j = 0; j < 4; j++) cp[j] = acc[i][j];
  }
}

// ---------------------------------------------------------------------------
// xQ = x[:, 512, :] @ W_Q^T   (fp32). One block per batch, 256 thr (4 waves),
// wave-per-output-column with lane-parallel K and shuffle reduce.
// Writes to ws copy and to d_out[40960..].
// ---------------------------------------------------------------------------
__global__ __launch_bounds__(256) void xq_kernel(const float* __restrict__ x,
                                                 const float* __restrict__ W_Q,
                                                 float* __restrict__ xQws,
                                                 float* __restrict__ outp) {
  const int b = blockIdx.x;
  const int tid = threadIdx.x;
  const int w = tid >> 6, lane = tid & 63;
  const float* xr = x + ((size_t)b * SFULL + TT) * DD;
  for (int n = w; n < KK; n += 4) {
    const float* wq = W_Q + (size_t)n * DD;
    float s = 0.f;
    for (int k = lane; k < DD; k += 64) s += wq[k] * xr[k];
#pragma unroll
    for (int off = 32; off; off >>= 1) s += __shfl_down(s, off);
    if (lane == 0) {
      xQws[b * KK + n] = s;
      outp[BB * OO + BB * DD + b * KK + n] = s;  // third output region
    }
  }
}

// ---------------------------------------------------------------------------
// Sequential winner-take-all scan. One block per batch (32 blocks, 1024 thr).
// Per step t: logits[h] = last[h]<0 ? L0t[b,t,h] : Gram[b,t,last[h]];
// argmax (first-index tie-break), last[winner]=t. Dumps last[] at the end.
//
// Distance-2 prefetch pipeline: step t issues global loads for row t+2 into
// registers; the row t+1 registers (issued at step t-1) are written into a
// double-buffered LDS copy at the tail of step t. Raw s_barrier with explicit
// lgkmcnt(0)-only waits keeps the global loads in flight across barriers
// (plain __syncthreads() lowers to a workgroup fence that drains vmcnt(0),
// which would serialize the ~900-cycle HBM row miss into every step).
// ---------------------------------------------------------------------------
#define SCAN_STEP(T, CUR, PI0, PI1, PIG, PO0, PO1, POG)                       \
  {                                                                           \
    /* issue global loads for row T+2 (clamped) — consumed at step T+1 */     \
    int rn = (T) + 2;                                                         \
    if (rn > TT - 1) rn = TT - 1;                                             \
    const double* lr = L0b + (size_t)rn * HH;                                 \
    PO0 = lr[tid];                                                            \
    PO1 = lr[tid + 1024];                                                     \
    const double* gr = Gb + (size_t)rn * TT;                                  \
    POG = (tid < TT) ? gr[tid] : 0.0;                                         \
    /* compute step T from LDS buffer CUR */                                  \
    int l1 = last[tid];                                                       \
    int l2 = last[tid + 1024];                                                \
    int g1 = l1 < 0 ? 0 : l1;                                                 \
    int g2 = l2 < 0 ? 0 : l2;                                                 \
    double v1 = (l1 < 0) ? Lb[CUR][tid] : Gr[CUR][g1];                        \
    double v2 = (l2 < 0) ? Lb[CUR][tid + 1024] : Gr[CUR][g2];                 \
    double v;                                                                 \
    int idx;                                                                  \
    if (v2 > v1) { v = v2; idx = tid + 1024; }                                \
    else { v = v1; idx = tid; } /* tie -> smaller index */                    \
    _Pragma("unroll")                                                         \
    for (int off = 32; off; off >>= 1) {                                      \
      double ov = __shfl_down(v, off);                                        \
      int oi = __shfl_down(idx, off);                                         \
      if (ov > v || (ov == v && oi < idx)) { v = ov; idx = oi; }              \
    }                                                                         \
    if ((tid & 63) == 0) { rv[tid >> 6] = v; ri[tid >> 6] = idx; }            \
    asm volatile("s_waitcnt lgkmcnt(0)" ::: "memory");                        \
    __builtin_amdgcn_s_barrier(); /* barrier A */                             \
    if (tid < 64) {                                                           \
      double vv = (tid < 16) ? rv[tid] : -INFINITY;                           \
      int ii = (tid < 16) ? ri[tid] : 0x7fffffff;                             \
      _Pragma("unroll")                                                       \
      for (int off = 8; off; off >>= 1) {                                     \
        double ov = __shfl_down(vv, off);                                     \
        int oi = __shfl_down(ii, off);                                        \
        if (ov > vv || (ov == vv && oi < ii)) { vv = ov; ii = oi; }           \
      }                                                                       \
      if (tid == 0) last[ii] = (T);                                           \
    }                                                                         \
    /* write row T+1 (landed long ago) into the other LDS buffer */           \
    Lb[(CUR) ^ 1][tid] = PI0;                                                 \
    Lb[(CUR) ^ 1][tid + 1024] = PI1;                                          \
    if (tid < TT) Gr[(CUR) ^ 1][tid] = PIG;                                   \
    asm volatile("s_waitcnt lgkmcnt(0)" ::: "memory");                        \
    __builtin_amdgcn_s_barrier(); /* barrier B */                             \
  }

__global__ __launch_bounds__(1024) void scan_kernel(const double* __restrict__ L0t,
                                                    const double* __restrict__ Gram,
                                                    int* __restrict__ lastmap) {
  const int b = blockIdx.x;
  const int tid = threadIdx.x;
  __shared__ double Lb[2][HH];  // 32 KB: double-buffered L0t row
  __shared__ double Gr[2][TT];  // 8 KB:  double-buffered Gram row
  __shared__ int last[HH];      // 8 KB
  __shared__ double rv[16];
  __shared__ int ri[16];

  const double* L0b = L0t + (size_t)b * TT * HH;
  const double* Gb = Gram + (size_t)b * TT * TT;

  last[tid] = -1;
  last[tid + 1024] = -1;

  double pA0, pA1, pAg;  // bank0: rows with (row)&1==0 landing slot
  double pB0, pB1, pBg;  // bank1

  // Prologue: row 0 direct to LDS buf0; issue row 1 into bank1.
  double r00 = L0b[tid];
  double r01 = L0b[tid + 1024];
  pB0 = L0b[HH + tid];
  pB1 = L0b[HH + tid + 1024];
  pBg = (tid < TT) ? Gb[TT + tid] : 0.0;  // Gram row 1
  Lb[0][tid] = r00;
  Lb[0][tid + 1024] = r01;
  // Gram row 0 never read (all last<0 at t=0).
  asm volatile("s_waitcnt lgkmcnt(0)" ::: "memory");
  __builtin_amdgcn_s_barrier();

  for (int t = 0; t < TT; t += 2) {
    SCAN_STEP(t,     0, pB0, pB1, pBg, pA0, pA1, pAg);
    SCAN_STEP(t + 1, 1, pA0, pA1, pAg, pB0, pB1, pBg);
  }

  lastmap[b * HH + tid] = last[tid];
  lastmap[b * HH + tid + 1024] = last[tid + 1024];
}

// ---------------------------------------------------------------------------
// Epilogue stage 1: q-logits, softmax -> hv; emit hvm (masked hv for
// untouched rows) and wgt[s] (hv of the row whose final content is step s).
// One block per batch, 1024 threads (16 waves).
// ---------------------------------------------------------------------------
__global__ __launch_bounds__(1024) void epi1_kernel(const float* __restrict__ W_hi0,
                                                    const double* __restrict__ xK64,
                                                    const float* __restrict__ xQws,
                                                    const int* __restrict__ lastmap,
                                                    float* __restrict__ hvmg,
                                                    float* __restrict__ wgtg) {
  const int b = blockIdx.x;
  const int tid = threadIdx.x;
  const int w = tid >> 6, lane = tid & 63;
  __shared__ float xq[KK];
  __shared__ float ql[HH];
  __shared__ float red[16];
  __shared__ float redsum[16];
  if (tid < KK) xq[tid] = xQws[b * KK + tid];
  if (tid < TT) wgtg[b * TT + tid] = 0.f;
  __syncthreads();

  for (int h = w; h < HH; h += 16) {
    int li = lastmap[b * HH + h];
    float s = 0.f;
    if (li < 0) {
      const float* p = W_hi0 + ((size_t)b * HH + h) * KK;
      for (int k = lane; k < KK; k += 64) s += p[k] * xq[k];
    } else {
      const double* p = xK64 + ((size_t)b * TT + li) * KK;
      for (int k = lane; k < KK; k += 64) s += (float)p[k] * xq[k];
    }
#pragma unroll
    for (int off = 32; off; off >>= 1) s += __shfl_down(s, off);
    if (lane == 0) ql[h] = s;
  }
  __syncthreads();

  // softmax over 2048
  float lm = fmaxf(ql[tid], ql[tid + 1024]);
#pragma unroll
  for (int off = 32; off; off >>= 1) lm = fmaxf(lm, __shfl_down(lm, off));
  if (lane == 0) red[w] = lm;
  __syncthreads();
  if (tid == 0) {
    float m = red[0];
    for (int i = 1; i < 16; i++) m = fmaxf(m, red[i]);
    red[0] = m;
  }
  __syncthreads();
  const float mx = red[0];
  float e1 = expf(ql[tid] - mx);
  float e2 = expf(ql[tid + 1024] - mx);
  float ls = e1 + e2;
#pragma unroll
  for (int off = 32; off; off >>= 1) ls += __shfl_down(ls, off);
  if (lane == 0) redsum[w] = ls;
  __syncthreads();
  if (tid == 0) {
    float s = 0.f;
    for (int i = 0; i < 16; i++) s += redsum[i];
    redsum[0] = s;
  }
  __syncthreads();
  const float inv = 1.f / redsum[0];
  const float hv1 = e1 * inv, hv2 = e2 * inv;
  const int li1 = lastmap[b * HH + tid];
  const int li2 = lastmap[b * HH + tid + 1024];
  hvmg[b * HH + tid] = (li1 < 0) ? hv1 : 0.f;
  hvmg[b * HH + tid + 1024] = (li2 < 0) ? hv2 : 0.f;
  if (li1 >= 0) wgtg[b * TT + li1] = hv1;  // last is injective: no races
  if (li2 >= 0) wgtg[b * TT + li2] = hv2;
}

// ---------------------------------------------------------------------------
// Epilogue stage 2: reinst_context[b,d] = sum_h hvm[h]*W_reinst0[b,h,d]
//                                       + sum_s wgt[s]*ctx[b,s,d]
// Grid (4, 32) x 256 threads: block handles 256 of 1024 d's for one batch.
// ---------------------------------------------------------------------------
__global__ __launch_bounds__(256) void epi2_kernel(const float* __restrict__ W_reinst0,
                                                   const float* __restrict__ x,
                                                   const float* __restrict__ hvmg,
                                                   const float* __restrict__ wgtg,
                                                   float* __restrict__ outp) {
  const int b = blockIdx.y;
  const int tid = threadIdx.x;
  const int d = blockIdx.x * 256 + tid;
  __shared__ float hvm[HH];
  __shared__ float wgt[TT];
  for (int i = tid; i < HH; i += 256) hvm[i] = hvmg[b * HH + i];
  for (int i = tid; i < TT; i += 256) wgt[i] = wgtg[b * TT + i];
  __syncthreads();
  float acc = 0.f;
#pragma unroll 4
  for (int h = 0; h < HH; h++) {
    float hm = hvm[h];
    if (hm != 0.f) acc += hm * W_reinst0[((size_t)b * HH + h) * DD + d];
  }
#pragma unroll 4
  for (int s = 0; s < TT; s++) {
    float wv = wgt[s];
    if (wv != 0.f) acc += wv * x[((size_t)b * SFULL + s) * DD + d];
  }
  outp[BB * OO + b * DD + d] = acc;  // second output region
}

// ---------------------------------------------------------------------------
// Epilogue stage 3: mhn_out then out = mhn_out @ W_proj^T.
// One block per batch, 1024 threads (16 waves).
// ---------------------------------------------------------------------------
__global__ __launch_bounds__(1024) void epi3_kernel(const float* __restrict__ W_oh0,
                                                    const float* __restrict__ xVws,
                                                    const float* __restrict__ W_proj,
                                                    const float* __restrict__ hvmg,
                                                    const float* __restrict__ wgtg,
                                                    float* __restrict__ outp) {
  const int b = blockIdx.x;
  const int tid = threadIdx.x;
  const int w = tid >> 6, lane = tid & 63;
  __shared__ float hvm[HH];
  __shared__ float wgt[TT];
  __shared__ float mhn[VV];
  for (int i = tid; i < HH; i += 1024) hvm[i] = hvmg[b * HH + i];
  if (tid < TT) wgt[tid] = wgtg[b * TT + tid];
  __syncthreads();

  // term 1: untouched columns of W_oh0
  for (int v = w; v < VV; v += 16) {
    const float* p = W_oh0 + ((size_t)b * VV + v) * HH;
    float s = 0.f;
    for (int h = lane; h < HH; h += 64) s += hvm[h] * p[h];
#pragma unroll
    for (int off = 32; off; off >>= 1) s += __shfl_down(s, off);
    if (lane == 0) mhn[v] = s;
  }
  __syncthreads();
  // term 2: replaced columns = xv rows weighted by wgt
  if (tid < VV) {
    float s2 = 0.f;
#pragma unroll 4
    for (int s = 0; s < TT; s++) {
      float wv = wgt[s];
      if (wv != 0.f) s2 += wv * xVws[((size_t)b * TT + s) * VV + tid];
    }
    mhn[tid] += s2;
  }
  __syncthreads();
  // projection
  for (int o = w; o < OO; o += 16) {
    const float* p = W_proj + (size_t)o * VV;
    float s = 0.f;
    for (int v = lane; v < VV; v += 64) s += mhn[v] * p[v];
#pragma unroll
    for (int off = 32; off; off >>= 1) s += __shfl_down(s, off);
    if (lane == 0) outp[b * OO + o] = s;  // first output region
  }
}

// ---------------------------------------------------------------------------
extern "C" void kernel_launch(void* const* d_in, const int* in_sizes, int n_in,
                              void* d_out, int out_size, void* d_ws, size_t ws_size,
                              hipStream_t stream) {
  const float* x        = (const float*)d_in[0];
  const float* W_Q      = (const float*)d_in[1];
  const float* W_K      = (const float*)d_in[2];
  const float* W_V      = (const float*)d_in[3];
  const float* W_proj   = (const float*)d_in[4];
  const float* W_hi0    = (const float*)d_in[5];
  const float* W_oh0    = (const float*)d_in[6];
  const float* W_reinst0 = (const float*)d_in[7];
  float* outp = (float*)d_out;

  // workspace layout (bytes)
  char* ws = (char*)d_ws;
  double* xK64 = (double*)ws;                                  // 32*512*256*8   = 33,554,432
  double* Gram = (double*)(ws + 33554432);                     // 32*512*512*8   = 67,108,864
  double* L0t  = (double*)(ws + 100663296);                    // 32*512*2048*8  = 268,435,456
  float*  xVws = (float*)(ws + 369098752);                     // 32*512*256*4   = 16,777,216
  float*  xQws = (float*)(ws + 385875968);                     // 32*256*4       = 32,768
  int*    lastmap = (int*)(ws + 385908736);                    // 32*2048*4      = 262,144
  float*  hvmg = (float*)(ws + 386170880);                     // 32*2048*4      = 262,144
  float*  wgtg = (float*)(ws + 386433024);                     // 32*512*4       = 65,536
  (void)ws_size; (void)in_sizes; (void)n_in; (void)out_size;

  // 1) xK (fp64) = ctx @ W_K^T : per batch M=512,N=256,K=1024
  gemm_abt<float, float, double><<<dim3(KK / 64, TT / 64, BB), 256, 0, stream>>>(
      x, (long long)SFULL * DD, DD,
      W_K, 0LL, DD,
      xK64, (long long)TT * KK, KK, DD);

  // 2) xV (fp32) = ctx @ W_V^T
  gemm_abt<float, float, float><<<dim3(VV / 64, TT / 64, BB), 256, 0, stream>>>(
      x, (long long)SFULL * DD, DD,
      W_V, 0LL, DD,
      xVws, (long long)TT * VV, VV, DD);

  // 3) xQ
  xq_kernel<<<BB, 256, 0, stream>>>(x, W_Q, xQws, outp);

  // 4) L0t[b,t,h] = <xK[b,t], W_hi0[b,h]>  : M=512, N=2048, K=256
  gemm_abt<double, float, double><<<dim3(HH / 64, TT / 64, BB), 256, 0, stream>>>(
      xK64, (long long)TT * KK, KK,
      W_hi0, (long long)HH * KK, KK,
      L0t, (long long)TT * HH, HH, KK);

  // 5) Gram[b,t,s] = <xK[b,t], xK[b,s]> : M=N=512, K=256
  gemm_abt<double, double, double><<<dim3(TT / 64, TT / 64, BB), 256, 0, stream>>>(
      xK64, (long long)TT * KK, KK,
      xK64, (long long)TT * KK, KK,
      Gram, (long long)TT * TT, TT, KK);

  // 6) sequential winner scan (distance-2 prefetch pipeline)
  scan_kernel<<<BB, 1024, 0, stream>>>(L0t, Gram, lastmap);

  // 7) q-logits + softmax -> hvm, wgt
  epi1_kernel<<<BB, 1024, 0, stream>>>(W_hi0, xK64, xQws, lastmap, hvmg, wgtg);

  // 8) reinst_context
  epi2_kernel<<<dim3(DD / 256, BB), 256, 0, stream>>>(W_reinst0, x, hvmg, wgtg, outp);

  // 9) mhn_out + projection
  epi3_kernel<<<BB, 1024, 0, stream>>>(W_oh0, xVws, W_proj, hvmg, wgtg, outp);
}

// Round 2
// 3397.449 us; speedup vs baseline: 1.3231x; 1.2545x over previous
//
#include <hip/hip_runtime.h>
#include <math.h>

// Shapes (fixed per reference setup_inputs):
#define BB 32
#define SFULL 513
#define TT 512
#define DD 1024
#define KK 256
#define VV 256
#define HH 2048
#define OO 256

// ---------------------------------------------------------------------------
// Generic tiled GEMM: C[m][n] = sum_k A[m][k] * B[n][k]   (A * B^T)
// 64x64 tile, BK=16, 256 threads, 4x4 micro-tile per thread.
// Batch via blockIdx.z with element strides. Accumulation in CT.
// All dims assumed divisible (M%64==0, N%64==0, K%16==0) — true for all uses.
// ---------------------------------------------------------------------------
template <typename AT, typename BT, typename CT>
__global__ __launch_bounds__(256) void gemm_abt(
    const AT* __restrict__ A, long long aBatch, int aPitch,
    const BT* __restrict__ Bm, long long bBatch, int bPitch,
    CT* __restrict__ C, long long cBatch, int cPitch, int Kd) {
  const int bz = blockIdx.z;
  A  += (size_t)bz * aBatch;
  Bm += (size_t)bz * bBatch;
  C  += (size_t)bz * cBatch;
  const int m0 = blockIdx.y * 64;
  const int n0 = blockIdx.x * 64;
  const int tid = threadIdx.x;
  const int tx = tid & 15;        // 0..15 -> n
  const int ty = tid >> 4;        // 0..15 -> m
  const int rl = tid >> 2;        // 0..63 row for loads
  const int kq = tid & 3;         // 0..3  k-quad for loads

  __shared__ AT As[16][65];
  __shared__ BT Bs[16][65];

  CT acc[4][4];
#pragma unroll
  for (int i = 0; i < 4; i++)
#pragma unroll
    for (int j = 0; j < 4; j++) acc[i][j] = (CT)0;

  for (int kk = 0; kk < Kd; kk += 16) {
    const AT* ap = A + (size_t)(m0 + rl) * aPitch + kk + kq * 4;
    const BT* bp = Bm + (size_t)(n0 + rl) * bPitch + kk + kq * 4;
#pragma unroll
    for (int i = 0; i < 4; i++) As[kq * 4 + i][rl] = ap[i];
#pragma unroll
    for (int i = 0; i < 4; i++) Bs[kq * 4 + i][rl] = bp[i];
    __syncthreads();
#pragma unroll
    for (int k = 0; k < 16; k++) {
      CT a[4], b[4];
#pragma unroll
      for (int i = 0; i < 4; i++) a[i] = (CT)As[k][ty * 4 + i];
#pragma unroll
      for (int j = 0; j < 4; j++) b[j] = (CT)Bs[k][tx * 4 + j];
#pragma unroll
      for (int i = 0; i < 4; i++)
#pragma unroll
        for (int j = 0; j < 4; j++) acc[i][j] += a[i] * b[j];
    }
    __syncthreads();
  }

#pragma unroll
  for (int i = 0; i < 4; i++) {
    CT* cp = C + (size_t)(m0 + ty * 4 + i) * cPitch + n0 + tx * 4;
#pragma unroll
    for (int j = 0; j < 4; j++) cp[j] = acc[i][j];
  }
}

// ---------------------------------------------------------------------------
// xQ = x[:, 512, :] @ W_Q^T   (fp32). One block per batch, 256 thr (4 waves),
// wave-per-output-column with lane-parallel K and shuffle reduce.
// Writes to ws copy and to d_out[40960..].
// ---------------------------------------------------------------------------
__global__ __launch_bounds__(256) void xq_kernel(const float* __restrict__ x,
                                                 const float* __restrict__ W_Q,
                                                 float* __restrict__ xQws,
                                                 float* __restrict__ outp) {
  const int b = blockIdx.x;
  const int tid = threadIdx.x;
  const int w = tid >> 6, lane = tid & 63;
  const float* xr = x + ((size_t)b * SFULL + TT) * DD;
  for (int n = w; n < KK; n += 4) {
    const float* wq = W_Q + (size_t)n * DD;
    float s = 0.f;
    for (int k = lane; k < DD; k += 64) s += wq[k] * xr[k];
#pragma unroll
    for (int off = 32; off; off >>= 1) s += __shfl_down(s, off);
    if (lane == 0) {
      xQws[b * KK + n] = s;
      outp[BB * OO + BB * DD + b * KK + n] = s;  // third output region
    }
  }
}

// ---------------------------------------------------------------------------
// Sequential winner-take-all scan. One block per batch (32 blocks, 1024 thr).
// Per step t: logits[h] = last[h]<0 ? L0t[b,t,h] : Gram[b,t,last[h]];
// argmax (first-index tie-break), last[winner]=t. Dumps last[] at the end.
//
// Distance-2 prefetch pipeline: step t issues global loads for row t+2 into
// registers; the row t+1 registers (issued at step t-1) are written into a
// double-buffered LDS copy at the tail of step t. Raw s_barrier with explicit
// lgkmcnt(0)-only waits keeps the global loads in flight across barriers
// (plain __syncthreads() lowers to a workgroup fence that drains vmcnt(0),
// which would serialize the ~900-cycle HBM row miss into every step).
// ---------------------------------------------------------------------------
#define SCAN_STEP(T, CUR, PI0, PI1, PIG, PO0, PO1, POG)                       \
  {                                                                           \
    /* issue global loads for row T+2 (clamped) — consumed at step T+1 */     \
    int rn = (T) + 2;                                                         \
    if (rn > TT - 1) rn = TT - 1;                                             \
    const double* lr = L0b + (size_t)rn * HH;                                 \
    PO0 = lr[tid];                                                            \
    PO1 = lr[tid + 1024];                                                     \
    const double* gr = Gb + (size_t)rn * TT;                                  \
    POG = (tid < TT) ? gr[tid] : 0.0;                                         \
    /* compute step T from LDS buffer CUR */                                  \
    int l1 = last[tid];                                                       \
    int l2 = last[tid + 1024];                                                \
    int g1 = l1 < 0 ? 0 : l1;                                                 \
    int g2 = l2 < 0 ? 0 : l2;                                                 \
    double v1 = (l1 < 0) ? Lb[CUR][tid] : Gr[CUR][g1];                        \
    double v2 = (l2 < 0) ? Lb[CUR][tid + 1024] : Gr[CUR][g2];                 \
    double v;                                                                 \
    int idx;                                                                  \
    if (v2 > v1) { v = v2; idx = tid + 1024; }                                \
    else { v = v1; idx = tid; } /* tie -> smaller index */                    \
    _Pragma("unroll")                                                         \
    for (int off = 32; off; off >>= 1) {                                      \
      double ov = __shfl_down(v, off);                                        \
      int oi = __shfl_down(idx, off);                                         \
      if (ov > v || (ov == v && oi < idx)) { v = ov; idx = oi; }              \
    }                                                                         \
    if ((tid & 63) == 0) { rv[tid >> 6] = v; ri[tid >> 6] = idx; }            \
    asm volatile("s_waitcnt lgkmcnt(0)" ::: "memory");                        \
    __builtin_amdgcn_s_barrier(); /* barrier A */                             \
    if (tid < 64) {                                                           \
      double vv = (tid < 16) ? rv[tid] : -INFINITY;                           \
      int ii = (tid < 16) ? ri[tid] : 0x7fffffff;                             \
      _Pragma("unroll")                                                       \
      for (int off = 8; off; off >>= 1) {                                     \
        double ov = __shfl_down(vv, off);                                     \
        int oi = __shfl_down(ii, off);                                        \
        if (ov > vv || (ov == vv && oi < ii)) { vv = ov; ii = oi; }           \
      }                                                                       \
      if (tid == 0) last[ii] = (T);                                           \
    }                                                                         \
    /* write row T+1 (landed long ago) into the other LDS buffer */           \
    Lb[(CUR) ^ 1][tid] = PI0;                                                 \
    Lb[(CUR) ^ 1][tid + 1024] = PI1;                                          \
    if (tid < TT) Gr[(CUR) ^ 1][tid] = PIG;                                   \
    asm volatile("s_waitcnt lgkmcnt(0)" ::: "memory");                        \
    __builtin_amdgcn_s_barrier(); /* barrier B */                             \
  }

__global__ __launch_bounds__(1024) void scan_kernel(const double* __restrict__ L0t,
                                                    const double* __restrict__ Gram,
                                                    int* __restrict__ lastmap) {
  const int b = blockIdx.x;
  const int tid = threadIdx.x;
  __shared__ double Lb[2][HH];  // 32 KB: double-buffered L0t row
  __shared__ double Gr[2][TT];  // 8 KB:  double-buffered Gram row
  __shared__ int last[HH];      // 8 KB
  __shared__ double rv[16];
  __shared__ int ri[16];

  const double* L0b = L0t + (size_t)b * TT * HH;
  const double* Gb = Gram + (size_t)b * TT * TT;

  last[tid] = -1;
  last[tid + 1024] = -1;

  double pA0, pA1, pAg;  // bank0: rows with (row)&1==0 landing slot
  double pB0, pB1, pBg;  // bank1

  // Prologue: row 0 direct to LDS buf0; issue row 1 into bank1.
  double r00 = L0b[tid];
  double r01 = L0b[tid + 1024];
  pB0 = L0b[HH + tid];
  pB1 = L0b[HH + tid + 1024];
  pBg = (tid < TT) ? Gb[TT + tid] : 0.0;  // Gram row 1
  Lb[0][tid] = r00;
  Lb[0][tid + 1024] = r01;
  // Gram row 0 never read (all last<0 at t=0).
  asm volatile("s_waitcnt lgkmcnt(0)" ::: "memory");
  __builtin_amdgcn_s_barrier();

  for (int t = 0; t < TT; t += 2) {
    SCAN_STEP(t,     0, pB0, pB1, pBg, pA0, pA1, pAg);
    SCAN_STEP(t + 1, 1, pA0, pA1, pAg, pB0, pB1, pBg);
  }

  lastmap[b * HH + tid] = last[tid];
  lastmap[b * HH + tid + 1024] = last[tid + 1024];
}

// ---------------------------------------------------------------------------
// Epilogue stage 1: q-logits, softmax -> hv; emit hvm (masked hv for
// untouched rows) and wgt[s] (hv of the row whose final content is step s).
// One block per batch, 1024 threads (16 waves).
// ---------------------------------------------------------------------------
__global__ __launch_bounds__(1024) void epi1_kernel(const float* __restrict__ W_hi0,
                                                    const double* __restrict__ xK64,
                                                    const float* __restrict__ xQws,
                                                    const int* __restrict__ lastmap,
                                                    float* __restrict__ hvmg,
                                                    float* __restrict__ wgtg) {
  const int b = blockIdx.x;
  const int tid = threadIdx.x;
  const int w = tid >> 6, lane = tid & 63;
  __shared__ float xq[KK];
  __shared__ float ql[HH];
  __shared__ float red[16];
  __shared__ float redsum[16];
  if (tid < KK) xq[tid] = xQws[b * KK + tid];
  if (tid < TT) wgtg[b * TT + tid] = 0.f;
  __syncthreads();

  for (int h = w; h < HH; h += 16) {
    int li = lastmap[b * HH + h];
    float s = 0.f;
    if (li < 0) {
      const float* p = W_hi0 + ((size_t)b * HH + h) * KK;
      for (int k = lane; k < KK; k += 64) s += p[k] * xq[k];
    } else {
      const double* p = xK64 + ((size_t)b * TT + li) * KK;
      for (int k = lane; k < KK; k += 64) s += (float)p[k] * xq[k];
    }
#pragma unroll
    for (int off = 32; off; off >>= 1) s += __shfl_down(s, off);
    if (lane == 0) ql[h] = s;
  }
  __syncthreads();

  // softmax over 2048
  float lm = fmaxf(ql[tid], ql[tid + 1024]);
#pragma unroll
  for (int off = 32; off; off >>= 1) lm = fmaxf(lm, __shfl_down(lm, off));
  if (lane == 0) red[w] = lm;
  __syncthreads();
  if (tid == 0) {
    float m = red[0];
    for (int i = 1; i < 16; i++) m = fmaxf(m, red[i]);
    red[0] = m;
  }
  __syncthreads();
  const float mx = red[0];
  float e1 = expf(ql[tid] - mx);
  float e2 = expf(ql[tid + 1024] - mx);
  float ls = e1 + e2;
#pragma unroll
  for (int off = 32; off; off >>= 1) ls += __shfl_down(ls, off);
  if (lane == 0) redsum[w] = ls;
  __syncthreads();
  if (tid == 0) {
    float s = 0.f;
    for (int i = 0; i < 16; i++) s += redsum[i];
    redsum[0] = s;
  }
  __syncthreads();
  const float inv = 1.f / redsum[0];
  const float hv1 = e1 * inv, hv2 = e2 * inv;
  const int li1 = lastmap[b * HH + tid];
  const int li2 = lastmap[b * HH + tid + 1024];
  hvmg[b * HH + tid] = (li1 < 0) ? hv1 : 0.f;
  hvmg[b * HH + tid + 1024] = (li2 < 0) ? hv2 : 0.f;
  if (li1 >= 0) wgtg[b * TT + li1] = hv1;  // last is injective: no races
  if (li2 >= 0) wgtg[b * TT + li2] = hv2;
}

// ---------------------------------------------------------------------------
// Epilogue stage 2 (rewritten for parallelism): reinst_context[b,d] =
//   sum_h hvm[h]*W_reinst0[b,h,d] + sum_s wgt[s]*ctx[b,s,d]
// The 2048 W_reinst0 rows ++ 512 ctx rows form one 2560-row space, split into
// 20 chunks x 128 rows. Grid (20, 32) x 256 thr; each thread owns 4 d's
// (float4 loads). Partials go to ws (aliasing the dead Gram region); a small
// reduce kernel sums 20 chunks. Chunk-ascending summation == original
// h-then-s ascending order, so rounding is bitwise identical.
// ---------------------------------------------------------------------------
#define RCH 20  // row chunks (2560 / 128)

__global__ __launch_bounds__(256) void epi2_partial(const float* __restrict__ W_reinst0,
                                                    const float* __restrict__ x,
                                                    const float* __restrict__ hvmg,
                                                    const float* __restrict__ wgtg,
                                                    float* __restrict__ partial) {
  const int c = blockIdx.x;   // 0..19
  const int b = blockIdx.y;   // 0..31
  const int tid = threadIdx.x;
  const int r0 = c * 128;
  __shared__ float wsh[128];
  if (tid < 128) {
    const int gr = r0 + tid;
    wsh[tid] = (gr < HH) ? hvmg[b * HH + gr] : wgtg[b * TT + (gr - HH)];
  }
  __syncthreads();
  const int d = tid * 4;
  float4 acc = make_float4(0.f, 0.f, 0.f, 0.f);
#pragma unroll 4
  for (int r = 0; r < 128; r++) {
    const float wv = wsh[r];
    if (wv == 0.f) continue;  // block-uniform branch; most softmax weights underflow
    const int gr = r0 + r;
    const float* src = (gr < HH)
        ? W_reinst0 + ((size_t)b * HH + gr) * DD
        : x + ((size_t)b * SFULL + (gr - HH)) * DD;
    const float4 v = *reinterpret_cast<const float4*>(src + d);
    acc.x += wv * v.x;
    acc.y += wv * v.y;
    acc.z += wv * v.z;
    acc.w += wv * v.w;
  }
  *reinterpret_cast<float4*>(partial + ((size_t)b * RCH + c) * DD + d) = acc;
}

__global__ __launch_bounds__(256) void epi2_reduce(const float* __restrict__ partial,
                                                   float* __restrict__ outp) {
  const int b = blockIdx.x;
  const int d = threadIdx.x * 4;
  float4 acc = make_float4(0.f, 0.f, 0.f, 0.f);
#pragma unroll
  for (int c = 0; c < RCH; c++) {
    const float4 v = *reinterpret_cast<const float4*>(partial + ((size_t)b * RCH + c) * DD + d);
    acc.x += v.x;
    acc.y += v.y;
    acc.z += v.z;
    acc.w += v.w;
  }
  *reinterpret_cast<float4*>(outp + BB * OO + b * DD + d) = acc;  // second output region
}

// ---------------------------------------------------------------------------
// Epilogue stage 3: mhn_out then out = mhn_out @ W_proj^T.
// One block per batch, 1024 threads (16 waves).
// ---------------------------------------------------------------------------
__global__ __launch_bounds__(1024) void epi3_kernel(const float* __restrict__ W_oh0,
                                                    const float* __restrict__ xVws,
                                                    const float* __restrict__ W_proj,
                                                    const float* __restrict__ hvmg,
                                                    const float* __restrict__ wgtg,
                                                    float* __restrict__ outp) {
  const int b = blockIdx.x;
  const int tid = threadIdx.x;
  const int w = tid >> 6, lane = tid & 63;
  __shared__ float hvm[HH];
  __shared__ float wgt[TT];
  __shared__ float mhn[VV];
  for (int i = tid; i < HH; i += 1024) hvm[i] = hvmg[b * HH + i];
  if (tid < TT) wgt[tid] = wgtg[b * TT + tid];
  __syncthreads();

  // term 1: untouched columns of W_oh0
  for (int v = w; v < VV; v += 16) {
    const float* p = W_oh0 + ((size_t)b * VV + v) * HH;
    float s = 0.f;
    for (int h = lane; h < HH; h += 64) s += hvm[h] * p[h];
#pragma unroll
    for (int off = 32; off; off >>= 1) s += __shfl_down(s, off);
    if (lane == 0) mhn[v] = s;
  }
  __syncthreads();
  // term 2: replaced columns = xv rows weighted by wgt
  if (tid < VV) {
    float s2 = 0.f;
#pragma unroll 4
    for (int s = 0; s < TT; s++) {
      float wv = wgt[s];
      if (wv != 0.f) s2 += wv * xVws[((size_t)b * TT + s) * VV + tid];
    }
    mhn[tid] += s2;
  }
  __syncthreads();
  // projection
  for (int o = w; o < OO; o += 16) {
    const float* p = W_proj + (size_t)o * VV;
    float s = 0.f;
    for (int v = lane; v < VV; v += 64) s += mhn[v] * p[v];
#pragma unroll
    for (int off = 32; off; off >>= 1) s += __shfl_down(s, off);
    if (lane == 0) outp[b * OO + o] = s;  // first output region
  }
}

// ---------------------------------------------------------------------------
extern "C" void kernel_launch(void* const* d_in, const int* in_sizes, int n_in,
                              void* d_out, int out_size, void* d_ws, size_t ws_size,
                              hipStream_t stream) {
  const float* x        = (const float*)d_in[0];
  const float* W_Q      = (const float*)d_in[1];
  const float* W_K      = (const float*)d_in[2];
  const float* W_V      = (const float*)d_in[3];
  const float* W_proj   = (const float*)d_in[4];
  const float* W_hi0    = (const float*)d_in[5];
  const float* W_oh0    = (const float*)d_in[6];
  const float* W_reinst0 = (const float*)d_in[7];
  float* outp = (float*)d_out;

  // workspace layout (bytes)
  char* ws = (char*)d_ws;
  double* xK64 = (double*)ws;                                  // 32*512*256*8   = 33,554,432
  double* Gram = (double*)(ws + 33554432);                     // 32*512*512*8   = 67,108,864
  double* L0t  = (double*)(ws + 100663296);                    // 32*512*2048*8  = 268,435,456
  float*  xVws = (float*)(ws + 369098752);                     // 32*512*256*4   = 16,777,216
  float*  xQws = (float*)(ws + 385875968);                     // 32*256*4       = 32,768
  int*    lastmap = (int*)(ws + 385908736);                    // 32*2048*4      = 262,144
  float*  hvmg = (float*)(ws + 386170880);                     // 32*2048*4      = 262,144
  float*  wgtg = (float*)(ws + 386433024);                     // 32*512*4       = 65,536
  // epi2 partials alias the Gram region (dead after scan_kernel):
  float*  partial = (float*)(ws + 33554432);                   // 32*20*1024*4   = 2,621,440
  (void)ws_size; (void)in_sizes; (void)n_in; (void)out_size;

  // 1) xK (fp64) = ctx @ W_K^T : per batch M=512,N=256,K=1024
  gemm_abt<float, float, double><<<dim3(KK / 64, TT / 64, BB), 256, 0, stream>>>(
      x, (long long)SFULL * DD, DD,
      W_K, 0LL, DD,
      xK64, (long long)TT * KK, KK, DD);

  // 2) xV (fp32) = ctx @ W_V^T
  gemm_abt<float, float, float><<<dim3(VV / 64, TT / 64, BB), 256, 0, stream>>>(
      x, (long long)SFULL * DD, DD,
      W_V, 0LL, DD,
      xVws, (long long)TT * VV, VV, DD);

  // 3) xQ
  xq_kernel<<<BB, 256, 0, stream>>>(x, W_Q, xQws, outp);

  // 4) L0t[b,t,h] = <xK[b,t], W_hi0[b,h]>  : M=512, N=2048, K=256
  gemm_abt<double, float, double><<<dim3(HH / 64, TT / 64, BB), 256, 0, stream>>>(
      xK64, (long long)TT * KK, KK,
      W_hi0, (long long)HH * KK, KK,
      L0t, (long long)TT * HH, HH, KK);

  // 5) Gram[b,t,s] = <xK[b,t], xK[b,s]> : M=N=512, K=256
  gemm_abt<double, double, double><<<dim3(TT / 64, TT / 64, BB), 256, 0, stream>>>(
      xK64, (long long)TT * KK, KK,
      xK64, (long long)TT * KK, KK,
      Gram, (long long)TT * TT, TT, KK);

  // 6) sequential winner scan (distance-2 prefetch pipeline)
  scan_kernel<<<BB, 1024, 0, stream>>>(L0t, Gram, lastmap);

  // 7) q-logits + softmax -> hvm, wgt
  epi1_kernel<<<BB, 1024, 0, stream>>>(W_hi0, xK64, xQws, lastmap, hvmg, wgtg);

  // 8) reinst_context: chunked partials + reduce (Gram region is dead now)
  epi2_partial<<<dim3(RCH, BB), 256, 0, stream>>>(W_reinst0, x, hvmg, wgtg, partial);
  epi2_reduce<<<BB, 256, 0, stream>>>(partial, outp);

  // 9) mhn_out + projection
  epi3_kernel<<<BB, 1024, 0, stream>>>(W_oh0, xVws, W_proj, hvmg, wgtg, outp);
}

// Round 3
// 3331.375 us; speedup vs baseline: 1.3494x; 1.0198x over previous
//
#include <hip/hip_runtime.h>
#include <math.h>

// Shapes (fixed per reference setup_inputs):
#define BB 32
#define SFULL 513
#define TT 512
#define DD 1024
#define KK 256
#define VV 256
#define HH 2048
#define OO 256

// ---------------------------------------------------------------------------
// Generic tiled GEMM: C[m][n] = sum_k A[m][k] * B[n][k]   (A * B^T)
// 64x64 tile, BK=16, 256 threads, 4x4 micro-tile per thread.
// Batch via blockIdx.z with element strides. Accumulation in CT.
// All dims assumed divisible (M%64==0, N%64==0, K%16==0) — true for all uses.
// ---------------------------------------------------------------------------
template <typename AT, typename BT, typename CT>
__global__ __launch_bounds__(256) void gemm_abt(
    const AT* __restrict__ A, long long aBatch, int aPitch,
    const BT* __restrict__ Bm, long long bBatch, int bPitch,
    CT* __restrict__ C, long long cBatch, int cPitch, int Kd) {
  const int bz = blockIdx.z;
  A  += (size_t)bz * aBatch;
  Bm += (size_t)bz * bBatch;
  C  += (size_t)bz * cBatch;
  const int m0 = blockIdx.y * 64;
  const int n0 = blockIdx.x * 64;
  const int tid = threadIdx.x;
  const int tx = tid & 15;        // 0..15 -> n
  const int ty = tid >> 4;        // 0..15 -> m
  const int rl = tid >> 2;        // 0..63 row for loads
  const int kq = tid & 3;         // 0..3  k-quad for loads

  __shared__ AT As[16][65];
  __shared__ BT Bs[16][65];

  CT acc[4][4];
#pragma unroll
  for (int i = 0; i < 4; i++)
#pragma unroll
    for (int j = 0; j < 4; j++) acc[i][j] = (CT)0;

  for (int kk = 0; kk < Kd; kk += 16) {
    const AT* ap = A + (size_t)(m0 + rl) * aPitch + kk + kq * 4;
    const BT* bp = Bm + (size_t)(n0 + rl) * bPitch + kk + kq * 4;
#pragma unroll
    for (int i = 0; i < 4; i++) As[kq * 4 + i][rl] = ap[i];
#pragma unroll
    for (int i = 0; i < 4; i++) Bs[kq * 4 + i][rl] = bp[i];
    __syncthreads();
#pragma unroll
    for (int k = 0; k < 16; k++) {
      CT a[4], b[4];
#pragma unroll
      for (int i = 0; i < 4; i++) a[i] = (CT)As[k][ty * 4 + i];
#pragma unroll
      for (int j = 0; j < 4; j++) b[j] = (CT)Bs[k][tx * 4 + j];
#pragma unroll
      for (int i = 0; i < 4; i++)
#pragma unroll
        for (int j = 0; j < 4; j++) acc[i][j] += a[i] * b[j];
    }
    __syncthreads();
  }

#pragma unroll
  for (int i = 0; i < 4; i++) {
    CT* cp = C + (size_t)(m0 + ty * 4 + i) * cPitch + n0 + tx * 4;
#pragma unroll
    for (int j = 0; j < 4; j++) cp[j] = acc[i][j];
  }
}

// ---------------------------------------------------------------------------
// xQ = x[:, 512, :] @ W_Q^T   (fp32). One block per batch, 256 thr (4 waves),
// wave-per-output-column with lane-parallel K and shuffle reduce.
// Writes to ws copy and to d_out[40960..].
// ---------------------------------------------------------------------------
__global__ __launch_bounds__(256) void xq_kernel(const float* __restrict__ x,
                                                 const float* __restrict__ W_Q,
                                                 float* __restrict__ xQws,
                                                 float* __restrict__ outp) {
  const int b = blockIdx.x;
  const int tid = threadIdx.x;
  const int w = tid >> 6, lane = tid & 63;
  const float* xr = x + ((size_t)b * SFULL + TT) * DD;
  for (int n = w; n < KK; n += 4) {
    const float* wq = W_Q + (size_t)n * DD;
    float s = 0.f;
    for (int k = lane; k < DD; k += 64) s += wq[k] * xr[k];
#pragma unroll
    for (int off = 32; off; off >>= 1) s += __shfl_down(s, off);
    if (lane == 0) {
      xQws[b * KK + n] = s;
      outp[BB * OO + BB * DD + b * KK + n] = s;  // third output region
    }
  }
}

// ---------------------------------------------------------------------------
// Sequential winner-take-all scan, v3: 256 threads (4 waves, ~1 per SIMD).
// Each thread owns 8 h-slots: h = i*512 + 2*tid + j (i=0..3, j=0..1).
// Register-resident state:
//   - L0 row double-buffered in regs (distance-2 prefetch, 4x dwordx4/thread)
//   - last[] in regs (winner broadcast -> owner updates locally)
// LDS: Gram row double-buffer (gather needs random addressing) + 4 wave slots
// (parity-double-buffered so ONE barrier/step suffices).
// Raw s_barrier + lgkmcnt(0)-only wait keeps global prefetch in flight.
// ---------------------------------------------------------------------------
#define STEP(T, CUR)                                                          \
  {                                                                           \
    double bv;                                                                \
    int bh;                                                                   \
    {                                                                         \
      double cand[4][2];                                                      \
      _Pragma("unroll")                                                       \
      for (int i = 0; i < 4; i++)                                             \
        _Pragma("unroll")                                                     \
        for (int j = 0; j < 2; j++) {                                         \
          int li = last[i][j];                                                \
          int s0 = li < 0 ? 0 : li;                                           \
          double gv = gbuf[CUR][s0];                                          \
          cand[i][j] = li < 0 ? l0[CUR][i][j] : gv;                           \
        }                                                                     \
      bv = cand[0][0];                                                        \
      bh = tid * 2;                                                           \
      _Pragma("unroll")                                                       \
      for (int i = 0; i < 4; i++)                                             \
        _Pragma("unroll")                                                     \
        for (int j = 0; j < 2; j++) {                                         \
          if (i == 0 && j == 0) continue;                                     \
          int h = i * 512 + tid * 2 + j;                                      \
          double c = cand[i][j];                                              \
          if (c > bv || (c == bv && h < bh)) { bv = c; bh = h; }              \
        }                                                                     \
    }                                                                         \
    /* 64-lane butterfly: all lanes converge to wave winner */                \
    _Pragma("unroll")                                                         \
    for (int m = 1; m < 64; m <<= 1) {                                        \
      double ov = __shfl_xor(bv, m);                                          \
      int oh = __shfl_xor(bh, m);                                             \
      if (ov > bv || (ov == bv && oh < bh)) { bv = ov; bh = oh; }             \
    }                                                                         \
    if (lane == 0) { sv[(T) & 1][w] = bv; sh[(T) & 1][w] = bh; }              \
    /* prefetch: L0 row T+2 -> l0[CUR] (freed this step);                     \
       Gram row T+2 -> gpre[CUR]; ds_write Gram row T+1 -> gbuf[CUR^1] */     \
    {                                                                         \
      int rn = (T) + 2;                                                       \
      if (rn > TT - 1) rn = TT - 1;                                           \
      const double* lp = L0b + (size_t)rn * HH + 2 * tid;                     \
      _Pragma("unroll")                                                       \
      for (int i = 0; i < 4; i++) {                                           \
        l0[CUR][i][0] = lp[i * 512];                                          \
        l0[CUR][i][1] = lp[i * 512 + 1];                                      \
      }                                                                       \
      const double* gp = Gb + (size_t)rn * TT + 2 * tid;                      \
      double t0 = gpre[(CUR) ^ 1][0], t1 = gpre[(CUR) ^ 1][1];                \
      gpre[CUR][0] = gp[0];                                                   \
      gpre[CUR][1] = gp[1];                                                   \
      gbuf[(CUR) ^ 1][2 * tid] = t0;                                          \
      gbuf[(CUR) ^ 1][2 * tid + 1] = t1;                                      \
    }                                                                         \
    asm volatile("s_waitcnt lgkmcnt(0)" ::: "memory");                        \
    __builtin_amdgcn_sched_barrier(0);                                        \
    __builtin_amdgcn_s_barrier();                                             \
    /* all threads combine the 4 wave slots identically */                    \
    bv = sv[(T) & 1][0];                                                      \
    bh = sh[(T) & 1][0];                                                      \
    _Pragma("unroll")                                                         \
    for (int q = 1; q < 4; q++) {                                             \
      double qv = sv[(T) & 1][q];                                             \
      int qh = sh[(T) & 1][q];                                                \
      if (qv > bv || (qv == bv && qh < bh)) { bv = qv; bh = qh; }             \
    }                                                                         \
    /* owner updates its register copy of last */                             \
    _Pragma("unroll")                                                         \
    for (int i = 0; i < 4; i++)                                               \
      _Pragma("unroll")                                                       \
      for (int j = 0; j < 2; j++)                                             \
        if (bh == i * 512 + tid * 2 + j) last[i][j] = (T);                    \
  }

__global__ __launch_bounds__(256) void scan_kernel(const double* __restrict__ L0t,
                                                   const double* __restrict__ Gram,
                                                   int* __restrict__ lastmap) {
  const int b = blockIdx.x;
  const int tid = threadIdx.x;
  const int lane = tid & 63;
  const int w = tid >> 6;
  __shared__ double gbuf[2][TT];  // 8 KB: Gram row double-buffer
  __shared__ double sv[2][4];     // wave-winner slots, parity-buffered
  __shared__ int sh[2][4];

  const double* L0b = L0t + (size_t)b * TT * HH;
  const double* Gb = Gram + (size_t)b * TT * TT;

  int last[4][2];
  double l0[2][4][2];   // L0 row double-buffer, 8 doubles/thread each
  double gpre[2][2];    // Gram prefetch registers

#pragma unroll
  for (int i = 0; i < 4; i++) { last[i][0] = -1; last[i][1] = -1; }

  // Prologue: L0 rows 0,1 -> regs; Gram row 1 -> gpre[1].
  // (Gram row 0 never used: all last<0 at t=0, gather results discarded.)
#pragma unroll
  for (int i = 0; i < 4; i++) {
    const double* p0 = L0b + (size_t)i * 512 + 2 * tid;
    l0[0][i][0] = p0[0];
    l0[0][i][1] = p0[1];
    const double* p1 = L0b + (size_t)HH + (size_t)i * 512 + 2 * tid;
    l0[1][i][0] = p1[0];
    l0[1][i][1] = p1[1];
  }
  gpre[1][0] = Gb[TT + 2 * tid];
  gpre[1][1] = Gb[TT + 2 * tid + 1];

  for (int t = 0; t < TT; t += 2) {
    STEP(t, 0);
    STEP(t + 1, 1);
  }

#pragma unroll
  for (int i = 0; i < 4; i++)
#pragma unroll
    for (int j = 0; j < 2; j++)
      lastmap[b * HH + i * 512 + tid * 2 + j] = last[i][j];
}

// ---------------------------------------------------------------------------
// Epilogue stage 1: q-logits, softmax -> hv; emit hvm (masked hv for
// untouched rows) and wgt[s] (hv of the row whose final content is step s).
// One block per batch, 1024 threads (16 waves).
// ---------------------------------------------------------------------------
__global__ __launch_bounds__(1024) void epi1_kernel(const float* __restrict__ W_hi0,
                                                    const double* __restrict__ xK64,
                                                    const float* __restrict__ xQws,
                                                    const int* __restrict__ lastmap,
                                                    float* __restrict__ hvmg,
                                                    float* __restrict__ wgtg) {
  const int b = blockIdx.x;
  const int tid = threadIdx.x;
  const int w = tid >> 6, lane = tid & 63;
  __shared__ float xq[KK];
  __shared__ float ql[HH];
  __shared__ float red[16];
  __shared__ float redsum[16];
  if (tid < KK) xq[tid] = xQws[b * KK + tid];
  if (tid < TT) wgtg[b * TT + tid] = 0.f;
  __syncthreads();

  for (int h = w; h < HH; h += 16) {
    int li = lastmap[b * HH + h];
    float s = 0.f;
    if (li < 0) {
      const float* p = W_hi0 + ((size_t)b * HH + h) * KK;
      for (int k = lane; k < KK; k += 64) s += p[k] * xq[k];
    } else {
      const double* p = xK64 + ((size_t)b * TT + li) * KK;
      for (int k = lane; k < KK; k += 64) s += (float)p[k] * xq[k];
    }
#pragma unroll
    for (int off = 32; off; off >>= 1) s += __shfl_down(s, off);
    if (lane == 0) ql[h] = s;
  }
  __syncthreads();

  // softmax over 2048
  float lm = fmaxf(ql[tid], ql[tid + 1024]);
#pragma unroll
  for (int off = 32; off; off >>= 1) lm = fmaxf(lm, __shfl_down(lm, off));
  if (lane == 0) red[w] = lm;
  __syncthreads();
  if (tid == 0) {
    float m = red[0];
    for (int i = 1; i < 16; i++) m = fmaxf(m, red[i]);
    red[0] = m;
  }
  __syncthreads();
  const float mx = red[0];
  float e1 = expf(ql[tid] - mx);
  float e2 = expf(ql[tid + 1024] - mx);
  float ls = e1 + e2;
#pragma unroll
  for (int off = 32; off; off >>= 1) ls += __shfl_down(ls, off);
  if (lane == 0) redsum[w] = ls;
  __syncthreads();
  if (tid == 0) {
    float s = 0.f;
    for (int i = 0; i < 16; i++) s += redsum[i];
    redsum[0] = s;
  }
  __syncthreads();
  const float inv = 1.f / redsum[0];
  const float hv1 = e1 * inv, hv2 = e2 * inv;
  const int li1 = lastmap[b * HH + tid];
  const int li2 = lastmap[b * HH + tid + 1024];
  hvmg[b * HH + tid] = (li1 < 0) ? hv1 : 0.f;
  hvmg[b * HH + tid + 1024] = (li2 < 0) ? hv2 : 0.f;
  if (li1 >= 0) wgtg[b * TT + li1] = hv1;  // last is injective: no races
  if (li2 >= 0) wgtg[b * TT + li2] = hv2;
}

// ---------------------------------------------------------------------------
// Epilogue stage 2: reinst_context[b,d] =
//   sum_h hvm[h]*W_reinst0[b,h,d] + sum_s wgt[s]*ctx[b,s,d]
// 2560-row space split into 20 chunks x 128 rows. Grid (20, 32) x 256 thr,
// float4 per thread; partials to ws (aliasing dead Gram region); reduce
// kernel sums chunks in ascending order (bitwise-identical rounding).
// ---------------------------------------------------------------------------
#define RCH 20  // row chunks (2560 / 128)

__global__ __launch_bounds__(256) void epi2_partial(const float* __restrict__ W_reinst0,
                                                    const float* __restrict__ x,
                                                    const float* __restrict__ hvmg,
                                                    const float* __restrict__ wgtg,
                                                    float* __restrict__ partial) {
  const int c = blockIdx.x;   // 0..19
  const int b = blockIdx.y;   // 0..31
  const int tid = threadIdx.x;
  const int r0 = c * 128;
  __shared__ float wsh[128];
  if (tid < 128) {
    const int gr = r0 + tid;
    wsh[tid] = (gr < HH) ? hvmg[b * HH + gr] : wgtg[b * TT + (gr - HH)];
  }
  __syncthreads();
  const int d = tid * 4;
  float4 acc = make_float4(0.f, 0.f, 0.f, 0.f);
#pragma unroll 4
  for (int r = 0; r < 128; r++) {
    const float wv = wsh[r];
    if (wv == 0.f) continue;  // block-uniform branch; most softmax weights underflow
    const int gr = r0 + r;
    const float* src = (gr < HH)
        ? W_reinst0 + ((size_t)b * HH + gr) * DD
        : x + ((size_t)b * SFULL + (gr - HH)) * DD;
    const float4 v = *reinterpret_cast<const float4*>(src + d);
    acc.x += wv * v.x;
    acc.y += wv * v.y;
    acc.z += wv * v.z;
    acc.w += wv * v.w;
  }
  *reinterpret_cast<float4*>(partial + ((size_t)b * RCH + c) * DD + d) = acc;
}

__global__ __launch_bounds__(256) void epi2_reduce(const float* __restrict__ partial,
                                                   float* __restrict__ outp) {
  const int b = blockIdx.x;
  const int d = threadIdx.x * 4;
  float4 acc = make_float4(0.f, 0.f, 0.f, 0.f);
#pragma unroll
  for (int c = 0; c < RCH; c++) {
    const float4 v = *reinterpret_cast<const float4*>(partial + ((size_t)b * RCH + c) * DD + d);
    acc.x += v.x;
    acc.y += v.y;
    acc.z += v.z;
    acc.w += v.w;
  }
  *reinterpret_cast<float4*>(outp + BB * OO + b * DD + d) = acc;  // second output region
}

// ---------------------------------------------------------------------------
// Epilogue stage 3: mhn_out then out = mhn_out @ W_proj^T.
// One block per batch, 1024 threads (16 waves).
// ---------------------------------------------------------------------------
__global__ __launch_bounds__(1024) void epi3_kernel(const float* __restrict__ W_oh0,
                                                    const float* __restrict__ xVws,
                                                    const float* __restrict__ W_proj,
                                                    const float* __restrict__ hvmg,
                                                    const float* __restrict__ wgtg,
                                                    float* __restrict__ outp) {
  const int b = blockIdx.x;
  const int tid = threadIdx.x;
  const int w = tid >> 6, lane = tid & 63;
  __shared__ float hvm[HH];
  __shared__ float wgt[TT];
  __shared__ float mhn[VV];
  for (int i = tid; i < HH; i += 1024) hvm[i] = hvmg[b * HH + i];
  if (tid < TT) wgt[tid] = wgtg[b * TT + tid];
  __syncthreads();

  // term 1: untouched columns of W_oh0
  for (int v = w; v < VV; v += 16) {
    const float* p = W_oh0 + ((size_t)b * VV + v) * HH;
    float s = 0.f;
    for (int h = lane; h < HH; h += 64) s += hvm[h] * p[h];
#pragma unroll
    for (int off = 32; off; off >>= 1) s += __shfl_down(s, off);
    if (lane == 0) mhn[v] = s;
  }
  __syncthreads();
  // term 2: replaced columns = xv rows weighted by wgt
  if (tid < VV) {
    float s2 = 0.f;
#pragma unroll 4
    for (int s = 0; s < TT; s++) {
      float wv = wgt[s];
      if (wv != 0.f) s2 += wv * xVws[((size_t)b * TT + s) * VV + tid];
    }
    mhn[tid] += s2;
  }
  __syncthreads();
  // projection
  for (int o = w; o < OO; o += 16) {
    const float* p = W_proj + (size_t)o * VV;
    float s = 0.f;
    for (int v = lane; v < VV; v += 64) s += mhn[v] * p[v];
#pragma unroll
    for (int off = 32; off; off >>= 1) s += __shfl_down(s, off);
    if (lane == 0) outp[b * OO + o] = s;  // first output region
  }
}

// ---------------------------------------------------------------------------
extern "C" void kernel_launch(void* const* d_in, const int* in_sizes, int n_in,
                              void* d_out, int out_size, void* d_ws, size_t ws_size,
                              hipStream_t stream) {
  const float* x        = (const float*)d_in[0];
  const float* W_Q      = (const float*)d_in[1];
  const float* W_K      = (const float*)d_in[2];
  const float* W_V      = (const float*)d_in[3];
  const float* W_proj   = (const float*)d_in[4];
  const float* W_hi0    = (const float*)d_in[5];
  const float* W_oh0    = (const float*)d_in[6];
  const float* W_reinst0 = (const float*)d_in[7];
  float* outp = (float*)d_out;

  // workspace layout (bytes)
  char* ws = (char*)d_ws;
  double* xK64 = (double*)ws;                                  // 32*512*256*8   = 33,554,432
  double* Gram = (double*)(ws + 33554432);                     // 32*512*512*8   = 67,108,864
  double* L0t  = (double*)(ws + 100663296);                    // 32*512*2048*8  = 268,435,456
  float*  xVws = (float*)(ws + 369098752);                     // 32*512*256*4   = 16,777,216
  float*  xQws = (float*)(ws + 385875968);                     // 32*256*4       = 32,768
  int*    lastmap = (int*)(ws + 385908736);                    // 32*2048*4      = 262,144
  float*  hvmg = (float*)(ws + 386170880);                     // 32*2048*4      = 262,144
  float*  wgtg = (float*)(ws + 386433024);                     // 32*512*4       = 65,536
  // epi2 partials alias the Gram region (dead after scan_kernel):
  float*  partial = (float*)(ws + 33554432);                   // 32*20*1024*4   = 2,621,440
  (void)ws_size; (void)in_sizes; (void)n_in; (void)out_size;

  // 1) xK (fp64) = ctx @ W_K^T : per batch M=512,N=256,K=1024
  gemm_abt<float, float, double><<<dim3(KK / 64, TT / 64, BB), 256, 0, stream>>>(
      x, (long long)SFULL * DD, DD,
      W_K, 0LL, DD,
      xK64, (long long)TT * KK, KK, DD);

  // 2) xV (fp32) = ctx @ W_V^T
  gemm_abt<float, float, float><<<dim3(VV / 64, TT / 64, BB), 256, 0, stream>>>(
      x, (long long)SFULL * DD, DD,
      W_V, 0LL, DD,
      xVws, (long long)TT * VV, VV, DD);

  // 3) xQ
  xq_kernel<<<BB, 256, 0, stream>>>(x, W_Q, xQws, outp);

  // 4) L0t[b,t,h] = <xK[b,t], W_hi0[b,h]>  : M=512, N=2048, K=256
  gemm_abt<double, float, double><<<dim3(HH / 64, TT / 64, BB), 256, 0, stream>>>(
      xK64, (long long)TT * KK, KK,
      W_hi0, (long long)HH * KK, KK,
      L0t, (long long)TT * HH, HH, KK);

  // 5) Gram[b,t,s] = <xK[b,t], xK[b,s]> : M=N=512, K=256
  gemm_abt<double, double, double><<<dim3(TT / 64, TT / 64, BB), 256, 0, stream>>>(
      xK64, (long long)TT * KK, KK,
      xK64, (long long)TT * KK, KK,
      Gram, (long long)TT * TT, TT, KK);

  // 6) sequential winner scan (4-wave register-resident pipeline)
  scan_kernel<<<BB, 256, 0, stream>>>(L0t, Gram, lastmap);

  // 7) q-logits + softmax -> hvm, wgt
  epi1_kernel<<<BB, 1024, 0, stream>>>(W_hi0, xK64, xQws, lastmap, hvmg, wgtg);

  // 8) reinst_context: chunked partials + reduce (Gram region is dead now)
  epi2_partial<<<dim3(RCH, BB), 256, 0, stream>>>(W_reinst0, x, hvmg, wgtg, partial);
  epi2_reduce<<<BB, 256, 0, stream>>>(partial, outp);

  // 9) mhn_out + projection
  epi3_kernel<<<BB, 1024, 0, stream>>>(W_oh0, xVws, W_proj, hvmg, wgtg, outp);
}

// Round 6
// 3005.663 us; speedup vs baseline: 1.4956x; 1.1084x over previous
//
#include <hip/hip_runtime.h>
#include <math.h>

// Shapes (fixed per reference setup_inputs):
#define BB 32
#define SFULL 513
#define TT 512
#define DD 1024
#define KK 256
#define VV 256
#define HH 2048
#define OO 256

// ---------------------------------------------------------------------------
// Generic tiled GEMM: C[m][n] = sum_k A[m][k] * B[n][k]   (A * B^T)
// 64x64 tile, BK=16, 256 threads, 4x4 micro-tile per thread.
// Batch via blockIdx.z with element strides. Accumulation in CT.
// All dims assumed divisible (M%64==0, N%64==0, K%16==0) — true for all uses.
// ---------------------------------------------------------------------------
template <typename AT, typename BT, typename CT>
__global__ __launch_bounds__(256) void gemm_abt(
    const AT* __restrict__ A, long long aBatch, int aPitch,
    const BT* __restrict__ Bm, long long bBatch, int bPitch,
    CT* __restrict__ C, long long cBatch, int cPitch, int Kd) {
  const int bz = blockIdx.z;
  A  += (size_t)bz * aBatch;
  Bm += (size_t)bz * bBatch;
  C  += (size_t)bz * cBatch;
  const int m0 = blockIdx.y * 64;
  const int n0 = blockIdx.x * 64;
  const int tid = threadIdx.x;
  const int tx = tid & 15;        // 0..15 -> n
  const int ty = tid >> 4;        // 0..15 -> m
  const int rl = tid >> 2;        // 0..63 row for loads
  const int kq = tid & 3;         // 0..3  k-quad for loads

  __shared__ AT As[16][65];
  __shared__ BT Bs[16][65];

  CT acc[4][4];
#pragma unroll
  for (int i = 0; i < 4; i++)
#pragma unroll
    for (int j = 0; j < 4; j++) acc[i][j] = (CT)0;

  for (int kk = 0; kk < Kd; kk += 16) {
    const AT* ap = A + (size_t)(m0 + rl) * aPitch + kk + kq * 4;
    const BT* bp = Bm + (size_t)(n0 + rl) * bPitch + kk + kq * 4;
#pragma unroll
    for (int i = 0; i < 4; i++) As[kq * 4 + i][rl] = ap[i];
#pragma unroll
    for (int i = 0; i < 4; i++) Bs[kq * 4 + i][rl] = bp[i];
    __syncthreads();
#pragma unroll
    for (int k = 0; k < 16; k++) {
      CT a[4], b[4];
#pragma unroll
      for (int i = 0; i < 4; i++) a[i] = (CT)As[k][ty * 4 + i];
#pragma unroll
      for (int j = 0; j < 4; j++) b[j] = (CT)Bs[k][tx * 4 + j];
#pragma unroll
      for (int i = 0; i < 4; i++)
#pragma unroll
        for (int j = 0; j < 4; j++) acc[i][j] += a[i] * b[j];
    }
    __syncthreads();
  }

#pragma unroll
  for (int i = 0; i < 4; i++) {
    CT* cp = C + (size_t)(m0 + ty * 4 + i) * cPitch + n0 + tx * 4;
#pragma unroll
    for (int j = 0; j < 4; j++) cp[j] = acc[i][j];
  }
}

// ---------------------------------------------------------------------------
// xQ = x[:, 512, :] @ W_Q^T   (fp32). One block per batch, 256 thr (4 waves),
// wave-per-output-column with lane-parallel K and shuffle reduce.
// Writes to ws copy and to d_out[40960..].
// ---------------------------------------------------------------------------
__global__ __launch_bounds__(256) void xq_kernel(const float* __restrict__ x,
                                                 const float* __restrict__ W_Q,
                                                 float* __restrict__ xQws,
                                                 float* __restrict__ outp) {
  const int b = blockIdx.x;
  const int tid = threadIdx.x;
  const int w = tid >> 6, lane = tid & 63;
  const float* xr = x + ((size_t)b * SFULL + TT) * DD;
  for (int n = w; n < KK; n += 4) {
    const float* wq = W_Q + (size_t)n * DD;
    float s = 0.f;
    for (int k = lane; k < DD; k += 64) s += wq[k] * xr[k];
#pragma unroll
    for (int off = 32; off; off >>= 1) s += __shfl_down(s, off);
    if (lane == 0) {
      xQws[b * KK + n] = s;
      outp[BB * OO + BB * DD + b * KK + n] = s;  // third output region
    }
  }
}

// ---------------------------------------------------------------------------
// Sequential winner-take-all scan, v5: 256 threads (4 waves).
// Each thread owns 8 h-slots: h = i*512 + 2*tid + j (i=0..3, j=0..1).
// (value,index) packed into ONE sortable u64 key (order-preserving f64->u64
// map; low 11 mantissa bits replaced by 2047-h, preserving the smaller-index
// tie-break and making keys unique). Cross-lane argmax: 4-level __shfl_xor
// butterfly within 16-lane groups (branchless u64 max, 2 dwords/level) +
// 16 LDS slots combined post-barrier by all threads via register tree.
// One barrier per step (slots parity-double-buffered).
// L0 row in registers (distance-2 prefetch); Gram row in LDS double-buffer.
// ---------------------------------------------------------------------------
__device__ __forceinline__ unsigned long long f64key(double v, int h) {
  unsigned long long b = (unsigned long long)__double_as_longlong(v);
  unsigned long long m = (unsigned long long)((long long)b >> 63);  // all-1 if neg
  b ^= (m | 0x8000000000000000ULL);           // order-preserving map
  return (b & ~2047ULL) | (unsigned long long)(2047 - h);  // unique key, idx tie-break
}

#define STEP(T, CUR)                                                          \
  {                                                                           \
    /* gather Gram[t][last] for the 8 owned slots */                          \
    double gv[4][2];                                                          \
    _Pragma("unroll")                                                         \
    for (int i = 0; i < 4; i++)                                               \
      _Pragma("unroll")                                                       \
      for (int j = 0; j < 2; j++) {                                           \
        int li = last[i][j];                                                  \
        int s0 = li < 0 ? 0 : li;                                             \
        gv[i][j] = gbuf[CUR][s0];                                             \
      }                                                                       \
    unsigned long long k;                                                     \
    {                                                                         \
      unsigned long long ck[4][2];                                            \
      _Pragma("unroll")                                                       \
      for (int i = 0; i < 4; i++)                                             \
        _Pragma("unroll")                                                     \
        for (int j = 0; j < 2; j++) {                                         \
          double sel = last[i][j] < 0 ? l0[CUR][i][j] : gv[i][j];             \
          ck[i][j] = f64key(sel, i * 512 + 2 * tid + j);                      \
        }                                                                     \
      unsigned long long a0 = ck[0][0] > ck[0][1] ? ck[0][0] : ck[0][1];      \
      unsigned long long a1 = ck[1][0] > ck[1][1] ? ck[1][0] : ck[1][1];      \
      unsigned long long a2 = ck[2][0] > ck[2][1] ? ck[2][0] : ck[2][1];      \
      unsigned long long a3 = ck[3][0] > ck[3][1] ? ck[3][0] : ck[3][1];      \
      unsigned long long b0 = a0 > a1 ? a0 : a1;                              \
      unsigned long long b1 = a2 > a3 ? a2 : a3;                              \
      k = b0 > b1 ? b0 : b1;                                                  \
    }                                                                         \
    /* 4-level butterfly within 16-lane groups: branchless u64 max */         \
    _Pragma("unroll")                                                         \
    for (int m = 1; m < 16; m <<= 1) {                                        \
      unsigned long long o = __shfl_xor(k, m);                                \
      if (o > k) k = o;                                                       \
    }                                                                         \
    if ((lane & 15) == 0) kslot[(T) & 1][tid >> 4] = k;                       \
    /* prefetch: L0 row T+2 -> l0[CUR]; Gram row T+2 -> gpre[CUR];            \
       ds_write Gram row T+1 (loaded last step) -> gbuf[CUR^1] */             \
    {                                                                         \
      int rn = (T) + 2;                                                       \
      if (rn > TT - 1) rn = TT - 1;                                           \
      const double* lp = L0b + (size_t)rn * HH + 2 * tid;                     \
      _Pragma("unroll")                                                       \
      for (int i = 0; i < 4; i++) {                                           \
        l0[CUR][i][0] = lp[i * 512];                                          \
        l0[CUR][i][1] = lp[i * 512 + 1];                                      \
      }                                                                       \
      const double* gp = Gb + (size_t)rn * TT + 2 * tid;                      \
      double t0 = gpre[(CUR) ^ 1][0], t1 = gpre[(CUR) ^ 1][1];                \
      gpre[CUR][0] = gp[0];                                                   \
      gpre[CUR][1] = gp[1];                                                   \
      gbuf[(CUR) ^ 1][2 * tid] = t0;                                          \
      gbuf[(CUR) ^ 1][2 * tid + 1] = t1;                                      \
    }                                                                         \
    asm volatile("s_waitcnt lgkmcnt(0)" ::: "memory");                        \
    __builtin_amdgcn_sched_barrier(0);                                        \
    __builtin_amdgcn_s_barrier();                                             \
    /* combine 16 slots (all threads, broadcast reads, register tree) */      \
    {                                                                         \
      unsigned long long s[16];                                               \
      _Pragma("unroll")                                                       \
      for (int q = 0; q < 16; q++) s[q] = kslot[(T) & 1][q];                  \
      _Pragma("unroll")                                                       \
      for (int st = 8; st; st >>= 1)                                          \
        _Pragma("unroll")                                                     \
        for (int q = 0; q < 8; q++)                                           \
          if (q < st && s[q + st] > s[q]) s[q] = s[q + st];                   \
      const int h = 2047 - (int)(s[0] & 2047ULL);                             \
      if (((h & 511) >> 1) == tid) last[h >> 9][h & 1] = (T);                 \
    }                                                                         \
  }

__global__ __launch_bounds__(256) void scan_kernel(const double* __restrict__ L0t,
                                                   const double* __restrict__ Gram,
                                                   int* __restrict__ lastmap) {
  const int b = blockIdx.x;
  const int tid = threadIdx.x;
  const int lane = tid & 63;
  __shared__ double gbuf[2][TT];              // 8 KB: Gram row double-buffer
  __shared__ unsigned long long kslot[2][16]; // 16-group winners, parity-buffered

  const double* L0b = L0t + (size_t)b * TT * HH;
  const double* Gb = Gram + (size_t)b * TT * TT;

  int last[4][2];
  double l0[2][4][2];   // L0 row double-buffer, 8 doubles/thread each
  double gpre[2][2];    // Gram prefetch registers

#pragma unroll
  for (int i = 0; i < 4; i++) { last[i][0] = -1; last[i][1] = -1; }

  // Prologue: L0 rows 0,1 -> regs; Gram row 1 -> gpre[1].
  // (Gram row 0 never used: all last<0 at t=0, gather results discarded;
  //  gbuf[0] reads at t=0 are discarded by the select.)
#pragma unroll
  for (int i = 0; i < 4; i++) {
    const double* p0 = L0b + (size_t)i * 512 + 2 * tid;
    l0[0][i][0] = p0[0];
    l0[0][i][1] = p0[1];
    const double* p1 = L0b + (size_t)HH + (size_t)i * 512 + 2 * tid;
    l0[1][i][0] = p1[0];
    l0[1][i][1] = p1[1];
  }
  gpre[1][0] = Gb[TT + 2 * tid];
  gpre[1][1] = Gb[TT + 2 * tid + 1];

  for (int t = 0; t < TT; t += 2) {
    STEP(t, 0);
    STEP(t + 1, 1);
  }

#pragma unroll
  for (int i = 0; i < 4; i++)
#pragma unroll
    for (int j = 0; j < 2; j++)
      lastmap[b * HH + i * 512 + tid * 2 + j] = last[i][j];
}

// ---------------------------------------------------------------------------
// Epilogue stage 1: q-logits, softmax -> hv; emit hvm (masked hv for
// untouched rows) and wgt[s] (hv of the row whose final content is step s).
// One block per batch, 1024 threads (16 waves).
// ---------------------------------------------------------------------------
__global__ __launch_bounds__(1024) void epi1_kernel(const float* __restrict__ W_hi0,
                                                    const double* __restrict__ xK64,
                                                    const float* __restrict__ xQws,
                                                    const int* __restrict__ lastmap,
                                                    float* __restrict__ hvmg,
                                                    float* __restrict__ wgtg) {
  const int b = blockIdx.x;
  const int tid = threadIdx.x;
  const int w = tid >> 6, lane = tid & 63;
  __shared__ float xq[KK];
  __shared__ float ql[HH];
  __shared__ float red[16];
  __shared__ float redsum[16];
  if (tid < KK) xq[tid] = xQws[b * KK + tid];
  if (tid < TT) wgtg[b * TT + tid] = 0.f;
  __syncthreads();

  for (int h = w; h < HH; h += 16) {
    int li = lastmap[b * HH + h];
    float s = 0.f;
    if (li < 0) {
      const float* p = W_hi0 + ((size_t)b * HH + h) * KK;
      for (int k = lane; k < KK; k += 64) s += p[k] * xq[k];
    } else {
      const double* p = xK64 + ((size_t)b * TT + li) * KK;
      for (int k = lane; k < KK; k += 64) s += (float)p[k] * xq[k];
    }
#pragma unroll
    for (int off = 32; off; off >>= 1) s += __shfl_down(s, off);
    if (lane == 0) ql[h] = s;
  }
  __syncthreads();

  // softmax over 2048
  float lm = fmaxf(ql[tid], ql[tid + 1024]);
#pragma unroll
  for (int off = 32; off; off >>= 1) lm = fmaxf(lm, __shfl_down(lm, off));
  if (lane == 0) red[w] = lm;
  __syncthreads();
  if (tid == 0) {
    float m = red[0];
    for (int i = 1; i < 16; i++) m = fmaxf(m, red[i]);
    red[0] = m;
  }
  __syncthreads();
  const float mx = red[0];
  float e1 = expf(ql[tid] - mx);
  float e2 = expf(ql[tid + 1024] - mx);
  float ls = e1 + e2;
#pragma unroll
  for (int off = 32; off; off >>= 1) ls += __shfl_down(ls, off);
  if (lane == 0) redsum[w] = ls;
  __syncthreads();
  if (tid == 0) {
    float s = 0.f;
    for (int i = 0; i < 16; i++) s += redsum[i];
    redsum[0] = s;
  }
  __syncthreads();
  const float inv = 1.f / redsum[0];
  const float hv1 = e1 * inv, hv2 = e2 * inv;
  const int li1 = lastmap[b * HH + tid];
  const int li2 = lastmap[b * HH + tid + 1024];
  hvmg[b * HH + tid] = (li1 < 0) ? hv1 : 0.f;
  hvmg[b * HH + tid + 1024] = (li2 < 0) ? hv2 : 0.f;
  if (li1 >= 0) wgtg[b * TT + li1] = hv1;  // last is injective: no races
  if (li2 >= 0) wgtg[b * TT + li2] = hv2;
}

// ---------------------------------------------------------------------------
// Epilogue stage 2: reinst_context[b,d] =
//   sum_h hvm[h]*W_reinst0[b,h,d] + sum_s wgt[s]*ctx[b,s,d]
// 2560-row space split into 20 chunks x 128 rows. Grid (20, 32) x 256 thr,
// float4 per thread; partials to ws (aliasing dead Gram region); reduce
// kernel sums chunks in ascending order (bitwise-identical rounding).
// ---------------------------------------------------------------------------
#define RCH 20  // row chunks (2560 / 128)

__global__ __launch_bounds__(256) void epi2_partial(const float* __restrict__ W_reinst0,
                                                    const float* __restrict__ x,
                                                    const float* __restrict__ hvmg,
                                                    const float* __restrict__ wgtg,
                                                    float* __restrict__ partial) {
  const int c = blockIdx.x;   // 0..19
  const int b = blockIdx.y;   // 0..31
  const int tid = threadIdx.x;
  const int r0 = c * 128;
  __shared__ float wsh[128];
  if (tid < 128) {
    const int gr = r0 + tid;
    wsh[tid] = (gr < HH) ? hvmg[b * HH + gr] : wgtg[b * TT + (gr - HH)];
  }
  __syncthreads();
  const int d = tid * 4;
  float4 acc = make_float4(0.f, 0.f, 0.f, 0.f);
#pragma unroll 4
  for (int r = 0; r < 128; r++) {
    const float wv = wsh[r];
    if (wv == 0.f) continue;  // block-uniform branch; most softmax weights underflow
    const int gr = r0 + r;
    const float* src = (gr < HH)
        ? W_reinst0 + ((size_t)b * HH + gr) * DD
        : x + ((size_t)b * SFULL + (gr - HH)) * DD;
    const float4 v = *reinterpret_cast<const float4*>(src + d);
    acc.x += wv * v.x;
    acc.y += wv * v.y;
    acc.z += wv * v.z;
    acc.w += wv * v.w;
  }
  *reinterpret_cast<float4*>(partial + ((size_t)b * RCH + c) * DD + d) = acc;
}

__global__ __launch_bounds__(256) void epi2_reduce(const float* __restrict__ partial,
                                                   float* __restrict__ outp) {
  const int b = blockIdx.x;
  const int d = threadIdx.x * 4;
  float4 acc = make_float4(0.f, 0.f, 0.f, 0.f);
#pragma unroll
  for (int c = 0; c < RCH; c++) {
    const float4 v = *reinterpret_cast<const float4*>(partial + ((size_t)b * RCH + c) * DD + d);
    acc.x += v.x;
    acc.y += v.y;
    acc.z += v.z;
    acc.w += v.w;
  }
  *reinterpret_cast<float4*>(outp + BB * OO + b * DD + d) = acc;  // second output region
}

// ---------------------------------------------------------------------------
// Epilogue stage 3: mhn_out then out = mhn_out @ W_proj^T.
// One block per batch, 1024 threads (16 waves).
// ---------------------------------------------------------------------------
__global__ __launch_bounds__(1024) void epi3_kernel(const float* __restrict__ W_oh0,
                                                    const float* __restrict__ xVws,
                                                    const float* __restrict__ W_proj,
                                                    const float* __restrict__ hvmg,
                                                    const float* __restrict__ wgtg,
                                                    float* __restrict__ outp) {
  const int b = blockIdx.x;
  const int tid = threadIdx.x;
  const int w = tid >> 6, lane = tid & 63;
  __shared__ float hvm[HH];
  __shared__ float wgt[TT];
  __shared__ float mhn[VV];
  for (int i = tid; i < HH; i += 1024) hvm[i] = hvmg[b * HH + i];
  if (tid < TT) wgt[tid] = wgtg[b * TT + tid];
  __syncthreads();

  // term 1: untouched columns of W_oh0
  for (int v = w; v < VV; v += 16) {
    const float* p = W_oh0 + ((size_t)b * VV + v) * HH;
    float s = 0.f;
    for (int h = lane; h < HH; h += 64) s += hvm[h] * p[h];
#pragma unroll
    for (int off = 32; off; off >>= 1) s += __shfl_down(s, off);
    if (lane == 0) mhn[v] = s;
  }
  __syncthreads();
  // term 2: replaced columns = xv rows weighted by wgt
  if (tid < VV) {
    float s2 = 0.f;
#pragma unroll 4
    for (int s = 0; s < TT; s++) {
      float wv = wgt[s];
      if (wv != 0.f) s2 += wv * xVws[((size_t)b * TT + s) * VV + tid];
    }
    mhn[tid] += s2;
  }
  __syncthreads();
  // projection
  for (int o = w; o < OO; o += 16) {
    const float* p = W_proj + (size_t)o * VV;
    float s = 0.f;
    for (int v = lane; v < VV; v += 64) s += mhn[v] * p[v];
#pragma unroll
    for (int off = 32; off; off >>= 1) s += __shfl_down(s, off);
    if (lane == 0) outp[b * OO + o] = s;  // first output region
  }
}

// ---------------------------------------------------------------------------
extern "C" void kernel_launch(void* const* d_in, const int* in_sizes, int n_in,
                              void* d_out, int out_size, void* d_ws, size_t ws_size,
                              hipStream_t stream) {
  const float* x        = (const float*)d_in[0];
  const float* W_Q      = (const float*)d_in[1];
  const float* W_K      = (const float*)d_in[2];
  const float* W_V      = (const float*)d_in[3];
  const float* W_proj   = (const float*)d_in[4];
  const float* W_hi0    = (const float*)d_in[5];
  const float* W_oh0    = (const float*)d_in[6];
  const float* W_reinst0 = (const float*)d_in[7];
  float* outp = (float*)d_out;

  // workspace layout (bytes)
  char* ws = (char*)d_ws;
  double* xK64 = (double*)ws;                                  // 32*512*256*8   = 33,554,432
  double* Gram = (double*)(ws + 33554432);                     // 32*512*512*8   = 67,108,864
  double* L0t  = (double*)(ws + 100663296);                    // 32*512*2048*8  = 268,435,456
  float*  xVws = (float*)(ws + 369098752);                     // 32*512*256*4   = 16,777,216
  float*  xQws = (float*)(ws + 385875968);                     // 32*256*4       = 32,768
  int*    lastmap = (int*)(ws + 385908736);                    // 32*2048*4      = 262,144
  float*  hvmg = (float*)(ws + 386170880);                     // 32*2048*4      = 262,144
  float*  wgtg = (float*)(ws + 386433024);                     // 32*512*4       = 65,536
  // epi2 partials alias the Gram region (dead after scan_kernel):
  float*  partial = (float*)(ws + 33554432);                   // 32*20*1024*4   = 2,621,440
  (void)ws_size; (void)in_sizes; (void)n_in; (void)out_size;

  // 1) xK (fp64) = ctx @ W_K^T : per batch M=512,N=256,K=1024
  gemm_abt<float, float, double><<<dim3(KK / 64, TT / 64, BB), 256, 0, stream>>>(
      x, (long long)SFULL * DD, DD,
      W_K, 0LL, DD,
      xK64, (long long)TT * KK, KK, DD);

  // 2) xV (fp32) = ctx @ W_V^T
  gemm_abt<float, float, float><<<dim3(VV / 64, TT / 64, BB), 256, 0, stream>>>(
      x, (long long)SFULL * DD, DD,
      W_V, 0LL, DD,
      xVws, (long long)TT * VV, VV, DD);

  // 3) xQ
  xq_kernel<<<BB, 256, 0, stream>>>(x, W_Q, xQws, outp);

  // 4) L0t[b,t,h] = <xK[b,t], W_hi0[b,h]>  : M=512, N=2048, K=256
  gemm_abt<double, float, double><<<dim3(HH / 64, TT / 64, BB), 256, 0, stream>>>(
      xK64, (long long)TT * KK, KK,
      W_hi0, (long long)HH * KK, KK,
      L0t, (long long)TT * HH, HH, KK);

  // 5) Gram[b,t,s] = <xK[b,t], xK[b,s]> : M=N=512, K=256
  gemm_abt<double, double, double><<<dim3(TT / 64, TT / 64, BB), 256, 0, stream>>>(
      xK64, (long long)TT * KK, KK,
      xK64, (long long)TT * KK, KK,
      Gram, (long long)TT * TT, TT, KK);

  // 6) sequential winner scan (u64-key + shfl_xor butterfly pipeline)
  scan_kernel<<<BB, 256, 0, stream>>>(L0t, Gram, lastmap);

  // 7) q-logits + softmax -> hvm, wgt
  epi1_kernel<<<BB, 1024, 0, stream>>>(W_hi0, xK64, xQws, lastmap, hvmg, wgtg);

  // 8) reinst_context: chunked partials + reduce (Gram region is dead now)
  epi2_partial<<<dim3(RCH, BB), 256, 0, stream>>>(W_reinst0, x, hvmg, wgtg, partial);
  epi2_reduce<<<BB, 256, 0, stream>>>(partial, outp);

  // 9) mhn_out + projection
  epi3_kernel<<<BB, 1024, 0, stream>>>(W_oh0, xVws, W_proj, hvmg, wgtg, outp);
}